// Round 1
// baseline (519.842 us; speedup 1.0000x reference)
//
#include <hip/hip_runtime.h>
#include <hip/hip_bf16.h>
#include <stdint.h>

// LongcatMoe: T=4096, H=1024, I=512, E=64 routed + 16 zero, top-2, CAP=320, scale=1.5.
// R5: single-pass weight reads. Mean expert load ~102 rows < 128, so 128M x 128N
// tiles read each weight tile exactly once (R4's 64M tiles read them twice).
// Grid reordered so blockIdx.x = expert: all n-blocks of an expert land on the
// same XCD (ids differ by 64 = 0 mod 8) -> A-tile / gbuf-tile L2 reuse.
// f2bf staging now uses v_cvt_pk_bf16_f32 (1 instr / 2 values, RNE-identical).

#define T_TOK 4096
#define HDIM  1024
#define IDIM  512
#define NE    64
#define NEZ   80
#define CAPE  320
#define SCALEF 1.5f

typedef __attribute__((ext_vector_type(8))) short bf16x8;
typedef __attribute__((ext_vector_type(4))) float floatx4;

static __device__ __forceinline__ unsigned short f2bf(float f) {
    unsigned int x = __float_as_uint(f);
    x += 0x7fffu + ((x >> 16) & 1u);   // RNE
    return (unsigned short)(x >> 16);
}
static __device__ __forceinline__ float bf2f(unsigned short u) {
    return __uint_as_float(((unsigned int)u) << 16);
}
// 8 fp32 -> 8 bf16 (RNE) via v_cvt_pk_bf16_f32: 4 instrs instead of ~40 VALU.
static __device__ __forceinline__ uint4 pack8(const float* f) {
    uint4 v;
    asm("v_cvt_pk_bf16_f32 %0, %1, %2" : "=v"(v.x) : "v"(f[0]), "v"(f[1]));
    asm("v_cvt_pk_bf16_f32 %0, %1, %2" : "=v"(v.y) : "v"(f[2]), "v"(f[3]));
    asm("v_cvt_pk_bf16_f32 %0, %1, %2" : "=v"(v.z) : "v"(f[4]), "v"(f[5]));
    asm("v_cvt_pk_bf16_f32 %0, %1, %2" : "=v"(v.w) : "v"(f[6]), "v"(f[7]));
    return v;
}
static __device__ __forceinline__ uint2 pack4(float4 f) {
    uint2 v;
    asm("v_cvt_pk_bf16_f32 %0, %1, %2" : "=v"(v.x) : "v"(f.x), "v"(f.y));
    asm("v_cvt_pk_bf16_f32 %0, %1, %2" : "=v"(v.y) : "v"(f.z), "v"(f.w));
    return v;
}

// ---------------- Router: fp32 logits, sigmoid, top-2, dispatch ----------------
__global__ __launch_bounds__(256) void router_kernel(
    const float* __restrict__ hidden, const float* __restrict__ rw,
    const float* __restrict__ bias, int* __restrict__ cnt,
    int* __restrict__ slot_tok, float* __restrict__ w_routed,
    float* __restrict__ zc)
{
    __shared__ float sc[16][NEZ];
    const int tid = threadIdx.x;
    const int w = tid >> 6, lane = tid & 63;
    const int t0 = blockIdx.x * 16 + w * 4;

    float xr[4][16];
#pragma unroll
    for (int tt = 0; tt < 4; ++tt)
#pragma unroll
        for (int j = 0; j < 16; ++j)
            xr[tt][j] = hidden[(size_t)(t0 + tt) * HDIM + j * 64 + lane];

    for (int e = 0; e < NEZ; ++e) {
        float a0 = 0.f, a1 = 0.f, a2 = 0.f, a3 = 0.f;
        const float* r = rw + (size_t)e * HDIM;
#pragma unroll
        for (int j = 0; j < 16; ++j) {
            float rv = r[j * 64 + lane];
            a0 += xr[0][j] * rv; a1 += xr[1][j] * rv;
            a2 += xr[2][j] * rv; a3 += xr[3][j] * rv;
        }
#pragma unroll
        for (int off = 32; off > 0; off >>= 1) {
            a0 += __shfl_xor(a0, off);
            a1 += __shfl_xor(a1, off);
            a2 += __shfl_xor(a2, off);
            a3 += __shfl_xor(a3, off);
        }
        if (lane == 0) {
            sc[w * 4 + 0][e] = 1.f / (1.f + expf(-a0));
            sc[w * 4 + 1][e] = 1.f / (1.f + expf(-a1));
            sc[w * 4 + 2][e] = 1.f / (1.f + expf(-a2));
            sc[w * 4 + 3][e] = 1.f / (1.f + expf(-a3));
        }
    }
    __syncthreads();

    if (tid < 16) {
        const int t = blockIdx.x * 16 + tid;
        float b1 = -1e30f, b2 = -1e30f; int i1 = 0, i2 = 0;
        for (int e = 0; e < NEZ; ++e) {
            float b = sc[tid][e] + bias[e];
            if (b > b1) { b2 = b1; i2 = i1; b1 = b; i1 = e; }
            else if (b > b2) { b2 = b; i2 = e; }
        }
        float z = 0.f;
        int idx2[2] = { i1, i2 };
        for (int k = 0; k < 2; ++k) {
            int e = idx2[k];
            float wgt = sc[tid][e];
            float wr = 0.f;
            if (e >= NE) {
                z += wgt;
            } else {
                int pos = atomicAdd(&cnt[e], 1);
                if (pos < CAPE) { slot_tok[e * CAPE + pos] = t * 2 + k; wr = wgt; }
            }
            w_routed[t * 2 + k] = wr;
        }
        zc[t] = z;
    }
}

// ---------------- Gate/Up GEMM: tile 128M x 128N, BK=32 ----------------
// LDS (ushorts): A 8 chunks [8][512] at 0; Bg 8 chunks at 4096; Bu 8 at 8192.
// Chunk = 16 rows(cols) x 32 k in frag order: lane l holds 8 values at l*16B.
#define GU_BG 4096
#define GU_BU 8192
__global__ __launch_bounds__(256, 2) void gateup_kernel(
    const float* __restrict__ hidden,
    const float* __restrict__ w_gate, const float* __restrict__ w_up,
    const int* __restrict__ cnt, const int* __restrict__ slot_tok,
    unsigned short* __restrict__ gbuf)
{
    const int e  = blockIdx.x;          // expert on .x: same-expert blocks share an XCD
    const int n0 = blockIdx.y * 128;
    const int m0 = blockIdx.z * 128;
    int cnt_e = cnt[e]; if (cnt_e > CAPE) cnt_e = CAPE;
    if (m0 >= cnt_e) return;

    __shared__ unsigned short lds[12288];  // 24 KB
    __shared__ int sTok[128];

    const int tid = threadIdx.x;
    const int lane = tid & 63, wid = tid >> 6;
    const int ml = lane & 15, quad = lane >> 4;
    const int wm = wid >> 1, wn = wid & 1;   // wave tile 64M x 64N (x gate,up)

    if (tid < 128) {
        int r = m0 + tid;
        sTok[tid] = (r < cnt_e) ? (slot_tok[e * CAPE + r] >> 1) : 0;
    }
    __syncthreads();

    // A loader: 128 rows x 8 k4-groups; thread handles rows (tid>>3)+32p, k4=tid&7
    const int ak4 = tid & 7;
    const float* ha[4];
    int aoff[4];
#pragma unroll
    for (int p = 0; p < 4; ++p) {
        int arow = (tid >> 3) + 32 * p;
        aoff[p] = (arow >> 4) * 512 + ((ak4 >> 1) * 16 + (arow & 15)) * 8 + (ak4 & 1) * 4;
        ha[p] = hidden + (size_t)sTok[arow] * HDIM + ak4 * 4;
    }
    // B loader: bn = tid&127 (n col), bk = tid>>7 (k half): k = bk*16 + jj
    const int bn = tid & 127, bk = tid >> 7;
    const int boff0 = (bn >> 4) * 512 + ((bk * 2) * 16 + (bn & 15)) * 8;  // jj=0..7
    const int boff1 = boff0 + 128;                                        // jj=8..15

    const size_t ebase = (size_t)e * HDIM * IDIM;
    const float* wg_p = w_gate + ebase + (size_t)(bk * 16) * IDIM + n0 + bn;
    const float* wu_p = w_up   + ebase + (size_t)(bk * 16) * IDIM + n0 + bn;

    float4 aR[4];
    float  gR[16], uR[16];

    // prefetch kc=0
#pragma unroll
    for (int p = 0; p < 4; ++p) aR[p] = *(const float4*)ha[p];
#pragma unroll
    for (int jj = 0; jj < 16; ++jj) {
        gR[jj] = wg_p[(size_t)jj * IDIM];
        uR[jj] = wu_p[(size_t)jj * IDIM];
    }

    floatx4 ag[4][4], au[4][4];
#pragma unroll
    for (int mt = 0; mt < 4; ++mt)
#pragma unroll
        for (int nt = 0; nt < 4; ++nt) {
            ag[mt][nt] = (floatx4){0.f, 0.f, 0.f, 0.f};
            au[mt][nt] = (floatx4){0.f, 0.f, 0.f, 0.f};
        }

    for (int kc = 0; kc < HDIM; kc += 32) {
        // stage regs -> LDS (fragment order)
        {
#pragma unroll
            for (int p = 0; p < 4; ++p)
                *(uint2*)&lds[aoff[p]] = pack4(aR[p]);
            *(uint4*)&lds[GU_BG + boff0] = pack8(gR);
            *(uint4*)&lds[GU_BG + boff1] = pack8(gR + 8);
            *(uint4*)&lds[GU_BU + boff0] = pack8(uR);
            *(uint4*)&lds[GU_BU + boff1] = pack8(uR + 8);
        }
        __syncthreads();

        // prefetch next K-step (stays in flight during MFMA)
        if (kc + 32 < HDIM) {
            wg_p += (size_t)32 * IDIM; wu_p += (size_t)32 * IDIM;
#pragma unroll
            for (int p = 0; p < 4; ++p) { ha[p] += 32; aR[p] = *(const float4*)ha[p]; }
#pragma unroll
            for (int jj = 0; jj < 16; ++jj) {
                gR[jj] = wg_p[(size_t)jj * IDIM];
                uR[jj] = wu_p[(size_t)jj * IDIM];
            }
        }

        // fragments (lane*16B, conflict-free)
        bf16x8 a[4], bg[4], bu[4];
#pragma unroll
        for (int mt = 0; mt < 4; ++mt)
            a[mt] = *(const bf16x8*)&lds[(wm * 4 + mt) * 512 + lane * 8];
#pragma unroll
        for (int nt = 0; nt < 4; ++nt) {
            bg[nt] = *(const bf16x8*)&lds[GU_BG + (wn * 4 + nt) * 512 + lane * 8];
            bu[nt] = *(const bf16x8*)&lds[GU_BU + (wn * 4 + nt) * 512 + lane * 8];
        }
#pragma unroll
        for (int mt = 0; mt < 4; ++mt)
#pragma unroll
            for (int nt = 0; nt < 4; ++nt) {
                ag[mt][nt] = __builtin_amdgcn_mfma_f32_16x16x32_bf16(a[mt], bg[nt], ag[mt][nt], 0, 0, 0);
                au[mt][nt] = __builtin_amdgcn_mfma_f32_16x16x32_bf16(a[mt], bu[nt], au[mt][nt], 0, 0, 0);
            }
        __syncthreads();
    }

    // epilogue: g = silu(gate) * up -> bf16 gbuf[e][row][n]
#pragma unroll
    for (int mt = 0; mt < 4; ++mt) {
#pragma unroll
        for (int r4 = 0; r4 < 4; ++r4) {
            int gm = m0 + wm * 64 + mt * 16 + quad * 4 + r4;
            if (gm < cnt_e) {
                unsigned short* grow = gbuf + (size_t)(e * CAPE + gm) * IDIM + n0 + wn * 64;
#pragma unroll
                for (int nt = 0; nt < 4; ++nt) {
                    float g = ag[mt][nt][r4];
                    float u = au[mt][nt][r4];
                    float s = g / (1.f + __expf(-g));
                    grow[nt * 16 + ml] = f2bf(s * u);
                }
            }
        }
    }
}

// ---------------- Down GEMM: tile 128M x 128N, BK=32 ----------------
// LDS (ushorts): A 8 chunks at 0 (4096); B 8 chunks at 4096.
#define DN_B 4096
__global__ __launch_bounds__(256, 2) void down_kernel(
    const unsigned short* __restrict__ gbuf, const float* __restrict__ w_down,
    const int* __restrict__ cnt, const int* __restrict__ slot_tok,
    unsigned short* __restrict__ y2)
{
    const int e  = blockIdx.x;
    const int n0 = blockIdx.y * 128;
    const int m0 = blockIdx.z * 128;
    int cnt_e = cnt[e]; if (cnt_e > CAPE) cnt_e = CAPE;
    if (m0 >= cnt_e) return;

    __shared__ unsigned short lds[8192];  // 16 KB
    __shared__ int sSlot[128];

    const int tid = threadIdx.x;
    const int lane = tid & 63, wid = tid >> 6;
    const int ml = lane & 15, quad = lane >> 4;
    const int wm = wid >> 1, wn = wid & 1;   // wave tile 64M x 64N

    if (tid < 128) {
        int r = m0 + tid;
        sSlot[tid] = (r < cnt_e) ? slot_tok[e * CAPE + r] : 0;
    }
    __syncthreads();

    // A loader: 128 rows x 4 u8-groups; thread handles rows (tid>>2)+64p, u8=tid&3
    const int au8 = tid & 3;
    const unsigned short* gp[2];
    int aoff[2];
#pragma unroll
    for (int p = 0; p < 2; ++p) {
        int arow = (tid >> 2) + 64 * p;
        aoff[p] = (arow >> 4) * 512 + (au8 * 16 + (arow & 15)) * 8;
        gp[p] = gbuf + (size_t)(e * CAPE + m0 + arow) * IDIM + au8 * 8;
    }
    // B loader: bn = tid&127, bk = tid>>7: k = bk*16 + jj
    const int bn = tid & 127, bk = tid >> 7;
    const int boff0 = (bn >> 4) * 512 + ((bk * 2) * 16 + (bn & 15)) * 8;
    const int boff1 = boff0 + 128;
    const float* wd_p = w_down + (size_t)e * IDIM * HDIM + (size_t)(bk * 16) * HDIM + n0 + bn;

    uint4 aR[2];
    float bR[16];

#pragma unroll
    for (int p = 0; p < 2; ++p) aR[p] = *(const uint4*)gp[p];
#pragma unroll
    for (int jj = 0; jj < 16; ++jj) bR[jj] = wd_p[(size_t)jj * HDIM];

    floatx4 acc[4][4];
#pragma unroll
    for (int mt = 0; mt < 4; ++mt)
#pragma unroll
        for (int nt = 0; nt < 4; ++nt)
            acc[mt][nt] = (floatx4){0.f, 0.f, 0.f, 0.f};

    for (int kc = 0; kc < IDIM; kc += 32) {
#pragma unroll
        for (int p = 0; p < 2; ++p)
            *(uint4*)&lds[aoff[p]] = aR[p];
        *(uint4*)&lds[DN_B + boff0] = pack8(bR);
        *(uint4*)&lds[DN_B + boff1] = pack8(bR + 8);
        __syncthreads();

        if (kc + 32 < IDIM) {
            wd_p += (size_t)32 * HDIM;
#pragma unroll
            for (int p = 0; p < 2; ++p) { gp[p] += 32; aR[p] = *(const uint4*)gp[p]; }
#pragma unroll
            for (int jj = 0; jj < 16; ++jj) bR[jj] = wd_p[(size_t)jj * HDIM];
        }

        bf16x8 a[4], b[4];
#pragma unroll
        for (int mt = 0; mt < 4; ++mt)
            a[mt] = *(const bf16x8*)&lds[(wm * 4 + mt) * 512 + lane * 8];
#pragma unroll
        for (int nt = 0; nt < 4; ++nt)
            b[nt] = *(const bf16x8*)&lds[DN_B + (wn * 4 + nt) * 512 + lane * 8];
#pragma unroll
        for (int mt = 0; mt < 4; ++mt)
#pragma unroll
            for (int nt = 0; nt < 4; ++nt)
                acc[mt][nt] = __builtin_amdgcn_mfma_f32_16x16x32_bf16(a[mt], b[nt], acc[mt][nt], 0, 0, 0);
        __syncthreads();
    }

    // epilogue: scatter rows to y2[slot][n]; sSlot indexed by LOCAL row
#pragma unroll
    for (int mt = 0; mt < 4; ++mt) {
#pragma unroll
        for (int r4 = 0; r4 < 4; ++r4) {
            int lrow = wm * 64 + mt * 16 + quad * 4 + r4;
            if (m0 + lrow < cnt_e) {
                int slot = sSlot[lrow];
                unsigned short* yrow = y2 + (size_t)slot * HDIM + n0 + wn * 64;
#pragma unroll
                for (int nt = 0; nt < 4; ++nt)
                    yrow[nt * 16 + ml] = f2bf(acc[mt][nt][r4]);
            }
        }
    }
}

// ---------------- Combine ----------------
__global__ __launch_bounds__(256) void combine_kernel(
    const float* __restrict__ hidden, const unsigned short* __restrict__ y2,
    const float* __restrict__ w_routed, const float* __restrict__ zc,
    float* __restrict__ out)
{
    int gid = blockIdx.x * 256 + threadIdx.x;
    int t = gid >> 8;
    int h = (gid & 255) * 4;
    float4 x = *(const float4*)(hidden + (size_t)t * HDIM + h);
    float w0 = w_routed[t * 2 + 0];
    float w1 = w_routed[t * 2 + 1];
    float z  = zc[t];
    ushort4 ya = *(const ushort4*)(y2 + (size_t)(t * 2 + 0) * HDIM + h);
    ushort4 yb = *(const ushort4*)(y2 + (size_t)(t * 2 + 1) * HDIM + h);
    float4 o;
    o.x = SCALEF * (z * x.x + w0 * bf2f(ya.x) + w1 * bf2f(yb.x));
    o.y = SCALEF * (z * x.y + w0 * bf2f(ya.y) + w1 * bf2f(yb.y));
    o.z = SCALEF * (z * x.z + w0 * bf2f(ya.z) + w1 * bf2f(yb.z));
    o.w = SCALEF * (z * x.w + w0 * bf2f(ya.w) + w1 * bf2f(yb.w));
    *(float4*)(out + (size_t)t * HDIM + h) = o;
}

// ---------------- workspace layout ----------------
#define OFF_CNT   0
#define OFF_SLOT  4096
#define OFF_WR    (OFF_SLOT + NE * CAPE * 4)
#define OFF_ZC    (OFF_WR + T_TOK * 2 * 4)
#define OFF_GBUF  (OFF_ZC + T_TOK * 4)
#define OFF_Y2    (OFF_GBUF + (size_t)NE * CAPE * IDIM * 2)

extern "C" void kernel_launch(void* const* d_in, const int* in_sizes, int n_in,
                              void* d_out, int out_size, void* d_ws, size_t ws_size,
                              hipStream_t stream) {
    const float* hidden = (const float*)d_in[0];
    const float* rw     = (const float*)d_in[1];
    const float* bias   = (const float*)d_in[2];
    const float* w_gate = (const float*)d_in[3];
    const float* w_up   = (const float*)d_in[4];
    const float* w_down = (const float*)d_in[5];
    float* out = (float*)d_out;

    char* ws = (char*)d_ws;
    int*   cnt      = (int*)(ws + OFF_CNT);
    int*   slot_tok = (int*)(ws + OFF_SLOT);
    float* w_rt     = (float*)(ws + OFF_WR);
    float* zc       = (float*)(ws + OFF_ZC);
    unsigned short* gbuf = (unsigned short*)(ws + OFF_GBUF);
    unsigned short* y2   = (unsigned short*)(ws + OFF_Y2);

    hipMemsetAsync(cnt, 0, NE * sizeof(int), stream);

    router_kernel<<<T_TOK / 16, 256, 0, stream>>>(hidden, rw, bias, cnt, slot_tok, w_rt, zc);

    // expert on blockIdx.x: same-expert n-blocks differ by 64 in linear id
    // (64 % 8 XCDs == 0) -> co-located on one XCD for A/gbuf L2 reuse.
    gateup_kernel<<<dim3(NE, IDIM / 128, (CAPE + 127) / 128), 256, 0, stream>>>(
        hidden, w_gate, w_up, cnt, slot_tok, gbuf);

    down_kernel<<<dim3(NE, HDIM / 128, (CAPE + 127) / 128), 256, 0, stream>>>(
        gbuf, w_down, cnt, slot_tok, y2);

    combine_kernel<<<(T_TOK * HDIM / 4) / 256, 256, 0, stream>>>(
        hidden, y2, w_rt, zc, out);
}

// Round 2
// 483.444 us; speedup vs baseline: 1.0753x; 1.0753x over previous
//
#include <hip/hip_runtime.h>
#include <hip/hip_bf16.h>
#include <stdint.h>

// LongcatMoe: T=4096, H=1024, I=512, E=64 routed + 16 zero, top-2, CAP=320, scale=1.5.
// R6: router rewrite. R5 counters showed router = 113.7 us (22% of total) at
// 9.9% occupancy, VALUBusy 22%: latency-bound on (a) 6-level dependent shfl
// chains per expert, (b) divergent libm expf under 1-lane exec mask, (c) 1280
// scalar strided loads. Now: lane-major k (float4 loads of full rows), experts
// batched 16-wide (32 independent butterfly chains -> throughput bound),
// __expf sigmoid, 8 tok/block (512 blocks, 2/CU). GEMM kernels unchanged.

#define T_TOK 4096
#define HDIM  1024
#define IDIM  512
#define NE    64
#define NEZ   80
#define CAPE  320
#define SCALEF 1.5f

typedef __attribute__((ext_vector_type(8))) short bf16x8;
typedef __attribute__((ext_vector_type(4))) float floatx4;

static __device__ __forceinline__ unsigned short f2bf(float f) {
    unsigned int x = __float_as_uint(f);
    x += 0x7fffu + ((x >> 16) & 1u);   // RNE
    return (unsigned short)(x >> 16);
}
static __device__ __forceinline__ float bf2f(unsigned short u) {
    return __uint_as_float(((unsigned int)u) << 16);
}
// 8 fp32 -> 8 bf16 (RNE) via v_cvt_pk_bf16_f32.
static __device__ __forceinline__ uint4 pack8(const float* f) {
    uint4 v;
    asm("v_cvt_pk_bf16_f32 %0, %1, %2" : "=v"(v.x) : "v"(f[0]), "v"(f[1]));
    asm("v_cvt_pk_bf16_f32 %0, %1, %2" : "=v"(v.y) : "v"(f[2]), "v"(f[3]));
    asm("v_cvt_pk_bf16_f32 %0, %1, %2" : "=v"(v.z) : "v"(f[4]), "v"(f[5]));
    asm("v_cvt_pk_bf16_f32 %0, %1, %2" : "=v"(v.w) : "v"(f[6]), "v"(f[7]));
    return v;
}
static __device__ __forceinline__ uint2 pack4(float4 f) {
    uint2 v;
    asm("v_cvt_pk_bf16_f32 %0, %1, %2" : "=v"(v.x) : "v"(f.x), "v"(f.y));
    asm("v_cvt_pk_bf16_f32 %0, %1, %2" : "=v"(v.y) : "v"(f.z), "v"(f.w));
    return v;
}

// ---------------- Router: fp32 logits, sigmoid, top-2, dispatch ----------------
// 8 tokens/block, 512 blocks. Wave w owns tokens t0=blk*8+w*2 .. +1.
// k layout lane-major: k = lane*16 + j  (j=0..15), so rows load as 4x float4.
__global__ __launch_bounds__(256) void router_kernel(
    const float* __restrict__ hidden, const float* __restrict__ rw,
    const float* __restrict__ bias, int* __restrict__ cnt,
    int* __restrict__ slot_tok, float* __restrict__ w_routed,
    float* __restrict__ zc)
{
    __shared__ float sc[8][NEZ];
    __shared__ float sbias[NEZ];
    const int tid = threadIdx.x;
    const int w = tid >> 6, lane = tid & 63;
    const int t0 = blockIdx.x * 8 + w * 2;

    if (tid < NEZ) sbias[tid] = bias[tid];

    float4 xr[2][4];
#pragma unroll
    for (int tt = 0; tt < 2; ++tt)
#pragma unroll
        for (int j4 = 0; j4 < 4; ++j4)
            xr[tt][j4] = *(const float4*)&hidden[(size_t)(t0 + tt) * HDIM + lane * 16 + j4 * 4];

    for (int eb = 0; eb < NEZ; eb += 16) {
        float acc[2][16];
#pragma unroll
        for (int tt = 0; tt < 2; ++tt)
#pragma unroll
            for (int ee = 0; ee < 16; ++ee) acc[tt][ee] = 0.f;

#pragma unroll
        for (int ee = 0; ee < 16; ++ee) {
            const float* r = rw + (size_t)(eb + ee) * HDIM + lane * 16;
#pragma unroll
            for (int j4 = 0; j4 < 4; ++j4) {
                float4 rv = *(const float4*)&r[j4 * 4];
                acc[0][ee] += xr[0][j4].x * rv.x + xr[0][j4].y * rv.y
                            + xr[0][j4].z * rv.z + xr[0][j4].w * rv.w;
                acc[1][ee] += xr[1][j4].x * rv.x + xr[1][j4].y * rv.y
                            + xr[1][j4].z * rv.z + xr[1][j4].w * rv.w;
            }
        }
        // 32 independent butterfly chains -> pipelined, throughput-bound
#pragma unroll
        for (int off = 32; off > 0; off >>= 1)
#pragma unroll
            for (int tt = 0; tt < 2; ++tt)
#pragma unroll
                for (int ee = 0; ee < 16; ++ee)
                    acc[tt][ee] += __shfl_xor(acc[tt][ee], off);

        if (lane == 0) {
#pragma unroll
            for (int tt = 0; tt < 2; ++tt)
#pragma unroll
                for (int ee = 0; ee < 16; ++ee)
                    sc[w * 2 + tt][eb + ee] = 1.f / (1.f + __expf(-acc[tt][ee]));
        }
    }
    __syncthreads();

    if (tid < 8) {
        const int t = blockIdx.x * 8 + tid;
        float b1 = -1e30f, b2 = -1e30f; int i1 = 0, i2 = 0;
        for (int e = 0; e < NEZ; ++e) {
            float b = sc[tid][e] + sbias[e];
            if (b > b1) { b2 = b1; i2 = i1; b1 = b; i1 = e; }
            else if (b > b2) { b2 = b; i2 = e; }
        }
        float z = 0.f;
        int idx2[2] = { i1, i2 };
        for (int k = 0; k < 2; ++k) {
            int e = idx2[k];
            float wgt = sc[tid][e];
            float wr = 0.f;
            if (e >= NE) {
                z += wgt;
            } else {
                int pos = atomicAdd(&cnt[e], 1);
                if (pos < CAPE) { slot_tok[e * CAPE + pos] = t * 2 + k; wr = wgt; }
            }
            w_routed[t * 2 + k] = wr;
        }
        zc[t] = z;
    }
}

// ---------------- Gate/Up GEMM: tile 128M x 128N, BK=32 ----------------
// LDS (ushorts): A 8 chunks [8][512] at 0; Bg 8 chunks at 4096; Bu 8 at 8192.
// Chunk = 16 rows(cols) x 32 k in frag order: lane l holds 8 values at l*16B.
#define GU_BG 4096
#define GU_BU 8192
__global__ __launch_bounds__(256, 2) void gateup_kernel(
    const float* __restrict__ hidden,
    const float* __restrict__ w_gate, const float* __restrict__ w_up,
    const int* __restrict__ cnt, const int* __restrict__ slot_tok,
    unsigned short* __restrict__ gbuf)
{
    const int e  = blockIdx.x;          // expert on .x: same-expert blocks share an XCD
    const int n0 = blockIdx.y * 128;
    const int m0 = blockIdx.z * 128;
    int cnt_e = cnt[e]; if (cnt_e > CAPE) cnt_e = CAPE;
    if (m0 >= cnt_e) return;

    __shared__ unsigned short lds[12288];  // 24 KB
    __shared__ int sTok[128];

    const int tid = threadIdx.x;
    const int lane = tid & 63, wid = tid >> 6;
    const int ml = lane & 15, quad = lane >> 4;
    const int wm = wid >> 1, wn = wid & 1;   // wave tile 64M x 64N (x gate,up)

    if (tid < 128) {
        int r = m0 + tid;
        sTok[tid] = (r < cnt_e) ? (slot_tok[e * CAPE + r] >> 1) : 0;
    }
    __syncthreads();

    // A loader: 128 rows x 8 k4-groups; thread handles rows (tid>>3)+32p, k4=tid&7
    const int ak4 = tid & 7;
    const float* ha[4];
    int aoff[4];
#pragma unroll
    for (int p = 0; p < 4; ++p) {
        int arow = (tid >> 3) + 32 * p;
        aoff[p] = (arow >> 4) * 512 + ((ak4 >> 1) * 16 + (arow & 15)) * 8 + (ak4 & 1) * 4;
        ha[p] = hidden + (size_t)sTok[arow] * HDIM + ak4 * 4;
    }
    // B loader: bn = tid&127 (n col), bk = tid>>7 (k half): k = bk*16 + jj
    const int bn = tid & 127, bk = tid >> 7;
    const int boff0 = (bn >> 4) * 512 + ((bk * 2) * 16 + (bn & 15)) * 8;  // jj=0..7
    const int boff1 = boff0 + 128;                                        // jj=8..15

    const size_t ebase = (size_t)e * HDIM * IDIM;
    const float* wg_p = w_gate + ebase + (size_t)(bk * 16) * IDIM + n0 + bn;
    const float* wu_p = w_up   + ebase + (size_t)(bk * 16) * IDIM + n0 + bn;

    float4 aR[4];
    float  gR[16], uR[16];

    // prefetch kc=0
#pragma unroll
    for (int p = 0; p < 4; ++p) aR[p] = *(const float4*)ha[p];
#pragma unroll
    for (int jj = 0; jj < 16; ++jj) {
        gR[jj] = wg_p[(size_t)jj * IDIM];
        uR[jj] = wu_p[(size_t)jj * IDIM];
    }

    floatx4 ag[4][4], au[4][4];
#pragma unroll
    for (int mt = 0; mt < 4; ++mt)
#pragma unroll
        for (int nt = 0; nt < 4; ++nt) {
            ag[mt][nt] = (floatx4){0.f, 0.f, 0.f, 0.f};
            au[mt][nt] = (floatx4){0.f, 0.f, 0.f, 0.f};
        }

    for (int kc = 0; kc < HDIM; kc += 32) {
        // stage regs -> LDS (fragment order)
        {
#pragma unroll
            for (int p = 0; p < 4; ++p)
                *(uint2*)&lds[aoff[p]] = pack4(aR[p]);
            *(uint4*)&lds[GU_BG + boff0] = pack8(gR);
            *(uint4*)&lds[GU_BG + boff1] = pack8(gR + 8);
            *(uint4*)&lds[GU_BU + boff0] = pack8(uR);
            *(uint4*)&lds[GU_BU + boff1] = pack8(uR + 8);
        }
        __syncthreads();

        // prefetch next K-step (stays in flight during MFMA)
        if (kc + 32 < HDIM) {
            wg_p += (size_t)32 * IDIM; wu_p += (size_t)32 * IDIM;
#pragma unroll
            for (int p = 0; p < 4; ++p) { ha[p] += 32; aR[p] = *(const float4*)ha[p]; }
#pragma unroll
            for (int jj = 0; jj < 16; ++jj) {
                gR[jj] = wg_p[(size_t)jj * IDIM];
                uR[jj] = wu_p[(size_t)jj * IDIM];
            }
        }

        // fragments (lane*16B, conflict-free)
        bf16x8 a[4], bg[4], bu[4];
#pragma unroll
        for (int mt = 0; mt < 4; ++mt)
            a[mt] = *(const bf16x8*)&lds[(wm * 4 + mt) * 512 + lane * 8];
#pragma unroll
        for (int nt = 0; nt < 4; ++nt) {
            bg[nt] = *(const bf16x8*)&lds[GU_BG + (wn * 4 + nt) * 512 + lane * 8];
            bu[nt] = *(const bf16x8*)&lds[GU_BU + (wn * 4 + nt) * 512 + lane * 8];
        }
#pragma unroll
        for (int mt = 0; mt < 4; ++mt)
#pragma unroll
            for (int nt = 0; nt < 4; ++nt) {
                ag[mt][nt] = __builtin_amdgcn_mfma_f32_16x16x32_bf16(a[mt], bg[nt], ag[mt][nt], 0, 0, 0);
                au[mt][nt] = __builtin_amdgcn_mfma_f32_16x16x32_bf16(a[mt], bu[nt], au[mt][nt], 0, 0, 0);
            }
        __syncthreads();
    }

    // epilogue: g = silu(gate) * up -> bf16 gbuf[e][row][n]
#pragma unroll
    for (int mt = 0; mt < 4; ++mt) {
#pragma unroll
        for (int r4 = 0; r4 < 4; ++r4) {
            int gm = m0 + wm * 64 + mt * 16 + quad * 4 + r4;
            if (gm < cnt_e) {
                unsigned short* grow = gbuf + (size_t)(e * CAPE + gm) * IDIM + n0 + wn * 64;
#pragma unroll
                for (int nt = 0; nt < 4; ++nt) {
                    float g = ag[mt][nt][r4];
                    float u = au[mt][nt][r4];
                    float s = g / (1.f + __expf(-g));
                    grow[nt * 16 + ml] = f2bf(s * u);
                }
            }
        }
    }
}

// ---------------- Down GEMM: tile 128M x 128N, BK=32 ----------------
// LDS (ushorts): A 8 chunks at 0 (4096); B 8 chunks at 4096.
#define DN_B 4096
__global__ __launch_bounds__(256, 2) void down_kernel(
    const unsigned short* __restrict__ gbuf, const float* __restrict__ w_down,
    const int* __restrict__ cnt, const int* __restrict__ slot_tok,
    unsigned short* __restrict__ y2)
{
    const int e  = blockIdx.x;
    const int n0 = blockIdx.y * 128;
    const int m0 = blockIdx.z * 128;
    int cnt_e = cnt[e]; if (cnt_e > CAPE) cnt_e = CAPE;
    if (m0 >= cnt_e) return;

    __shared__ unsigned short lds[8192];  // 16 KB
    __shared__ int sSlot[128];

    const int tid = threadIdx.x;
    const int lane = tid & 63, wid = tid >> 6;
    const int ml = lane & 15, quad = lane >> 4;
    const int wm = wid >> 1, wn = wid & 1;   // wave tile 64M x 64N

    if (tid < 128) {
        int r = m0 + tid;
        sSlot[tid] = (r < cnt_e) ? slot_tok[e * CAPE + r] : 0;
    }
    __syncthreads();

    // A loader: 128 rows x 4 u8-groups; thread handles rows (tid>>2)+64p, u8=tid&3
    const int au8 = tid & 3;
    const unsigned short* gp[2];
    int aoff[2];
#pragma unroll
    for (int p = 0; p < 2; ++p) {
        int arow = (tid >> 2) + 64 * p;
        aoff[p] = (arow >> 4) * 512 + (au8 * 16 + (arow & 15)) * 8;
        gp[p] = gbuf + (size_t)(e * CAPE + m0 + arow) * IDIM + au8 * 8;
    }
    // B loader: bn = tid&127, bk = tid>>7: k = bk*16 + jj
    const int bn = tid & 127, bk = tid >> 7;
    const int boff0 = (bn >> 4) * 512 + ((bk * 2) * 16 + (bn & 15)) * 8;
    const int boff1 = boff0 + 128;
    const float* wd_p = w_down + (size_t)e * IDIM * HDIM + (size_t)(bk * 16) * HDIM + n0 + bn;

    uint4 aR[2];
    float bR[16];

#pragma unroll
    for (int p = 0; p < 2; ++p) aR[p] = *(const uint4*)gp[p];
#pragma unroll
    for (int jj = 0; jj < 16; ++jj) bR[jj] = wd_p[(size_t)jj * HDIM];

    floatx4 acc[4][4];
#pragma unroll
    for (int mt = 0; mt < 4; ++mt)
#pragma unroll
        for (int nt = 0; nt < 4; ++nt)
            acc[mt][nt] = (floatx4){0.f, 0.f, 0.f, 0.f};

    for (int kc = 0; kc < IDIM; kc += 32) {
#pragma unroll
        for (int p = 0; p < 2; ++p)
            *(uint4*)&lds[aoff[p]] = aR[p];
        *(uint4*)&lds[DN_B + boff0] = pack8(bR);
        *(uint4*)&lds[DN_B + boff1] = pack8(bR + 8);
        __syncthreads();

        if (kc + 32 < IDIM) {
            wd_p += (size_t)32 * HDIM;
#pragma unroll
            for (int p = 0; p < 2; ++p) { gp[p] += 32; aR[p] = *(const uint4*)gp[p]; }
#pragma unroll
            for (int jj = 0; jj < 16; ++jj) bR[jj] = wd_p[(size_t)jj * HDIM];
        }

        bf16x8 a[4], b[4];
#pragma unroll
        for (int mt = 0; mt < 4; ++mt)
            a[mt] = *(const bf16x8*)&lds[(wm * 4 + mt) * 512 + lane * 8];
#pragma unroll
        for (int nt = 0; nt < 4; ++nt)
            b[nt] = *(const bf16x8*)&lds[DN_B + (wn * 4 + nt) * 512 + lane * 8];
#pragma unroll
        for (int mt = 0; mt < 4; ++mt)
#pragma unroll
            for (int nt = 0; nt < 4; ++nt)
                acc[mt][nt] = __builtin_amdgcn_mfma_f32_16x16x32_bf16(a[mt], b[nt], acc[mt][nt], 0, 0, 0);
        __syncthreads();
    }

    // epilogue: scatter rows to y2[slot][n]; sSlot indexed by LOCAL row
#pragma unroll
    for (int mt = 0; mt < 4; ++mt) {
#pragma unroll
        for (int r4 = 0; r4 < 4; ++r4) {
            int lrow = wm * 64 + mt * 16 + quad * 4 + r4;
            if (m0 + lrow < cnt_e) {
                int slot = sSlot[lrow];
                unsigned short* yrow = y2 + (size_t)slot * HDIM + n0 + wn * 64;
#pragma unroll
                for (int nt = 0; nt < 4; ++nt)
                    yrow[nt * 16 + ml] = f2bf(acc[mt][nt][r4]);
            }
        }
    }
}

// ---------------- Combine ----------------
__global__ __launch_bounds__(256) void combine_kernel(
    const float* __restrict__ hidden, const unsigned short* __restrict__ y2,
    const float* __restrict__ w_routed, const float* __restrict__ zc,
    float* __restrict__ out)
{
    int gid = blockIdx.x * 256 + threadIdx.x;
    int t = gid >> 8;
    int h = (gid & 255) * 4;
    float4 x = *(const float4*)(hidden + (size_t)t * HDIM + h);
    float w0 = w_routed[t * 2 + 0];
    float w1 = w_routed[t * 2 + 1];
    float z  = zc[t];
    ushort4 ya = *(const ushort4*)(y2 + (size_t)(t * 2 + 0) * HDIM + h);
    ushort4 yb = *(const ushort4*)(y2 + (size_t)(t * 2 + 1) * HDIM + h);
    float4 o;
    o.x = SCALEF * (z * x.x + w0 * bf2f(ya.x) + w1 * bf2f(yb.x));
    o.y = SCALEF * (z * x.y + w0 * bf2f(ya.y) + w1 * bf2f(yb.y));
    o.z = SCALEF * (z * x.z + w0 * bf2f(ya.z) + w1 * bf2f(yb.z));
    o.w = SCALEF * (z * x.w + w0 * bf2f(ya.w) + w1 * bf2f(yb.w));
    *(float4*)(out + (size_t)t * HDIM + h) = o;
}

// ---------------- workspace layout ----------------
#define OFF_CNT   0
#define OFF_SLOT  4096
#define OFF_WR    (OFF_SLOT + NE * CAPE * 4)
#define OFF_ZC    (OFF_WR + T_TOK * 2 * 4)
#define OFF_GBUF  (OFF_ZC + T_TOK * 4)
#define OFF_Y2    (OFF_GBUF + (size_t)NE * CAPE * IDIM * 2)

extern "C" void kernel_launch(void* const* d_in, const int* in_sizes, int n_in,
                              void* d_out, int out_size, void* d_ws, size_t ws_size,
                              hipStream_t stream) {
    const float* hidden = (const float*)d_in[0];
    const float* rw     = (const float*)d_in[1];
    const float* bias   = (const float*)d_in[2];
    const float* w_gate = (const float*)d_in[3];
    const float* w_up   = (const float*)d_in[4];
    const float* w_down = (const float*)d_in[5];
    float* out = (float*)d_out;

    char* ws = (char*)d_ws;
    int*   cnt      = (int*)(ws + OFF_CNT);
    int*   slot_tok = (int*)(ws + OFF_SLOT);
    float* w_rt     = (float*)(ws + OFF_WR);
    float* zc       = (float*)(ws + OFF_ZC);
    unsigned short* gbuf = (unsigned short*)(ws + OFF_GBUF);
    unsigned short* y2   = (unsigned short*)(ws + OFF_Y2);

    hipMemsetAsync(cnt, 0, NE * sizeof(int), stream);

    router_kernel<<<T_TOK / 8, 256, 0, stream>>>(hidden, rw, bias, cnt, slot_tok, w_rt, zc);

    // expert on blockIdx.x: same-expert n-blocks differ by 64 in linear id
    // (64 % 8 XCDs == 0) -> co-located on one XCD for A/gbuf L2 reuse.
    gateup_kernel<<<dim3(NE, IDIM / 128, (CAPE + 127) / 128), 256, 0, stream>>>(
        hidden, w_gate, w_up, cnt, slot_tok, gbuf);

    down_kernel<<<dim3(NE, HDIM / 128, (CAPE + 127) / 128), 256, 0, stream>>>(
        gbuf, w_down, cnt, slot_tok, y2);

    combine_kernel<<<(T_TOK * HDIM / 4) / 256, 256, 0, stream>>>(
        hidden, y2, w_rt, zc, out);
}